// Round 6
// baseline (428.919 us; speedup 1.0000x reference)
//
#include <hip/hip_runtime.h>

#define RES 32
#define R3 (RES * RES * RES)
#define HALF (R3 / 2)

// Native no-return fp32 atomic add (ds_add_f32 / global_atomic_add_f32).
__device__ __forceinline__ void fadd_native(float* p, float v) {
    unsafeAtomicAdd(p, v);
}

// ---------------------------------------------------------------------------
// K1a: partial coordinate sums, float4 loads. grid (8, B), block 256.
// NUMERICALLY FROZEN: summation order determines mean -> rintf voxel
// boundaries. Do not restructure (absmax margin is thin).
// ---------------------------------------------------------------------------
__global__ void sums_kernel(const float* __restrict__ coords,
                            float* __restrict__ accum, int N) {
    const int b = blockIdx.y;
    const int stride = gridDim.x * blockDim.x;
    const float* cb = coords + (size_t)b * 3 * N;
    const int nvec = N >> 2;
    const float4* c0 = (const float4*)cb;
    const float4* c1 = (const float4*)(cb + N);
    const float4* c2 = (const float4*)(cb + 2 * N);

    float s0 = 0.f, s1 = 0.f, s2 = 0.f;
    for (int n = blockIdx.x * blockDim.x + threadIdx.x; n < nvec; n += stride) {
        float4 a = c0[n]; s0 += (a.x + a.y) + (a.z + a.w);
        float4 c = c1[n]; s1 += (c.x + c.y) + (c.z + c.w);
        float4 d = c2[n]; s2 += (d.x + d.y) + (d.z + d.w);
    }
    if (blockIdx.x == 0 && threadIdx.x == 0) {
        for (int n = nvec << 2; n < N; ++n) {
            s0 += cb[n]; s1 += cb[N + n]; s2 += cb[2 * N + n];
        }
    }
    for (int off = 32; off; off >>= 1) {
        s0 += __shfl_down(s0, off);
        s1 += __shfl_down(s1, off);
        s2 += __shfl_down(s2, off);
    }
    __shared__ float r0[4], r1[4], r2[4];
    const int lane = threadIdx.x & 63, wv = threadIdx.x >> 6;
    if (lane == 0) { r0[wv] = s0; r1[wv] = s1; r2[wv] = s2; }
    __syncthreads();
    if (threadIdx.x == 0) {
        float t0 = 0.f, t1 = 0.f, t2 = 0.f;
        const int nw = blockDim.x >> 6;
        for (int w = 0; w < nw; ++w) { t0 += r0[w]; t1 += r1[w]; t2 += r2[w]; }
        fadd_native(&accum[b * 4 + 0], t0);
        fadd_native(&accum[b * 4 + 1], t1);
        fadd_native(&accum[b * 4 + 2], t2);
    }
}

// ---------------------------------------------------------------------------
// K1b: partial max squared centered norm. NUMERICALLY FROZEN.
// ---------------------------------------------------------------------------
__global__ void maxn_kernel(const float* __restrict__ coords,
                            const float* __restrict__ accum,
                            unsigned* __restrict__ maxsq, int N) {
    const int b = blockIdx.y;
    const int stride = gridDim.x * blockDim.x;
    const float* cb = coords + (size_t)b * 3 * N;
    const float m0 = accum[b * 4 + 0] / (float)N;
    const float m1 = accum[b * 4 + 1] / (float)N;
    const float m2 = accum[b * 4 + 2] / (float)N;
    const int nvec = N >> 2;
    const float4* c0 = (const float4*)cb;
    const float4* c1 = (const float4*)(cb + N);
    const float4* c2 = (const float4*)(cb + 2 * N);

    float mx = 0.f;
    for (int n = blockIdx.x * blockDim.x + threadIdx.x; n < nvec; n += stride) {
        float4 a = c0[n], c = c1[n], d = c2[n];
        a.x -= m0; a.y -= m0; a.z -= m0; a.w -= m0;
        c.x -= m1; c.y -= m1; c.z -= m1; c.w -= m1;
        d.x -= m2; d.y -= m2; d.z -= m2; d.w -= m2;
        mx = fmaxf(mx, a.x * a.x + c.x * c.x + d.x * d.x);
        mx = fmaxf(mx, a.y * a.y + c.y * c.y + d.y * d.y);
        mx = fmaxf(mx, a.z * a.z + c.z * c.z + d.z * d.z);
        mx = fmaxf(mx, a.w * a.w + c.w * c.w + d.w * d.w);
    }
    if (blockIdx.x == 0 && threadIdx.x == 0) {
        for (int n = nvec << 2; n < N; ++n) {
            float a = cb[n] - m0, c = cb[N + n] - m1, d = cb[2 * N + n] - m2;
            mx = fmaxf(mx, a * a + c * c + d * d);
        }
    }
    for (int off = 32; off; off >>= 1) mx = fmaxf(mx, __shfl_down(mx, off));
    __shared__ float r0[4];
    const int lane = threadIdx.x & 63, wv = threadIdx.x >> 6;
    if (lane == 0) r0[wv] = mx;
    __syncthreads();
    if (threadIdx.x == 0) {
        const int nw = blockDim.x >> 6;
        for (int w = 0; w < nw; ++w) mx = fmaxf(mx, r0[w]);
        atomicMax(&maxsq[b], __float_as_uint(mx));
    }
}

// ---------------------------------------------------------------------------
// K2: per-point normalize + voxel index + counts. NUMERICALLY FROZEN.
// ---------------------------------------------------------------------------
__global__ void point_kernel(const float* __restrict__ coords,
                             const float* __restrict__ accum,
                             const unsigned* __restrict__ maxsq,
                             float* __restrict__ nc_out,
                             int* __restrict__ idx_out,
                             int* __restrict__ counts, int N) {
    const int n4 = blockIdx.x * blockDim.x + threadIdx.x;
    const int b = blockIdx.y;
    const int nvec = (N + 3) >> 2;
    if (n4 >= nvec) return;

    const float* cb = coords + (size_t)b * 3 * N;
    const float m0 = accum[b * 4 + 0] / (float)N;
    const float m1 = accum[b * 4 + 1] / (float)N;
    const float m2 = accum[b * 4 + 2] / (float)N;
    const float denom = 2.0f * sqrtf(__uint_as_float(maxsq[b]));
    float* ncb = nc_out + (size_t)b * 3 * N;
    int* irow = idx_out + (size_t)b * N;
    int* crow = counts + (size_t)b * R3;

    const int n0 = n4 << 2;
    if (n0 + 3 < N) {
        float4 a = *(const float4*)(cb + n0);
        float4 c = *(const float4*)(cb + N + n0);
        float4 d = *(const float4*)(cb + 2 * N + n0);
        float4 v0, v1, v2;
        int4 id;
        #define PROC(comp)                                                        \
        {                                                                         \
            float x = (a.comp - m0) / denom + 0.5f;                               \
            float y = (c.comp - m1) / denom + 0.5f;                               \
            float z = (d.comp - m2) / denom + 0.5f;                               \
            v0.comp = fminf(fmaxf(x * (float)RES, 0.f), (float)(RES - 1));        \
            v1.comp = fminf(fmaxf(y * (float)RES, 0.f), (float)(RES - 1));        \
            v2.comp = fminf(fmaxf(z * (float)RES, 0.f), (float)(RES - 1));        \
            id.comp = (int)rintf(v0.comp) * RES * RES                             \
                    + (int)rintf(v1.comp) * RES + (int)rintf(v2.comp);            \
        }
        PROC(x) PROC(y) PROC(z) PROC(w)
        #undef PROC
        *(float4*)(ncb + n0) = v0;
        *(float4*)(ncb + N + n0) = v1;
        *(float4*)(ncb + 2 * N + n0) = v2;
        *(int4*)(irow + n0) = id;
        atomicAdd(&crow[id.x], 1);
        atomicAdd(&crow[id.y], 1);
        atomicAdd(&crow[id.z], 1);
        atomicAdd(&crow[id.w], 1);
    } else {
        for (int n = n0; n < N; ++n) {
            float x = (cb[n] - m0) / denom + 0.5f;
            float y = (cb[N + n] - m1) / denom + 0.5f;
            float z = (cb[2 * N + n] - m2) / denom + 0.5f;
            float v0 = fminf(fmaxf(x * (float)RES, 0.f), (float)(RES - 1));
            float v1 = fminf(fmaxf(y * (float)RES, 0.f), (float)(RES - 1));
            float v2 = fminf(fmaxf(z * (float)RES, 0.f), (float)(RES - 1));
            ncb[n] = v0; ncb[N + n] = v1; ncb[2 * N + n] = v2;
            int id = (int)rintf(v0) * RES * RES + (int)rintf(v1) * RES + (int)rintf(v2);
            irow[n] = id;
            atomicAdd(&crow[id], 1);
        }
    }
}

// ---------------------------------------------------------------------------
// K2.5: in-place exclusive prefix scan of counts -> segment offsets.
// ---------------------------------------------------------------------------
__global__ __launch_bounds__(1024) void prefix_kernel(int* __restrict__ cnt) {
    const int b = blockIdx.x;
    int* row = cnt + (size_t)b * R3;
    const int tid = threadIdx.x;

    int c[32];
    int4* r4 = (int4*)(row + tid * 32);
    int sum = 0;
    #pragma unroll
    for (int k = 0; k < 8; ++k) {
        int4 v = r4[k];
        c[k * 4 + 0] = v.x; c[k * 4 + 1] = v.y;
        c[k * 4 + 2] = v.z; c[k * 4 + 3] = v.w;
        sum += (v.x + v.y) + (v.z + v.w);
    }

    __shared__ int sc[1024];
    sc[tid] = sum;
    __syncthreads();
    for (int off = 1; off < 1024; off <<= 1) {
        int v = (tid >= off) ? sc[tid - off] : 0;
        __syncthreads();
        sc[tid] += v;
        __syncthreads();
    }
    int run = sc[tid] - sum;   // exclusive base for this thread's chunk

    #pragma unroll
    for (int k = 0; k < 8; ++k) {
        int4 o;
        o.x = run; run += c[k * 4 + 0];
        o.y = run; run += c[k * 4 + 1];
        o.z = run; run += c[k * 4 + 2];
        o.w = run; run += c[k * 4 + 3];
        r4[k] = o;
    }
}

// ---------------------------------------------------------------------------
// K2.6: permute features into CSR (voxel-sorted) point-major order.
// Block = 64 points x 64 d. All global accesses >=256B contiguous chunks.
// After this kernel off[v] == segment end (cursor trick).
// ---------------------------------------------------------------------------
__global__ __launch_bounds__(256) void permute_kernel(
        const float* __restrict__ feats,   // (B, 64, N)
        const int* __restrict__ idx,       // (B, N) voxel ids from point_kernel
        int* __restrict__ off,             // (B, R3) exclusive offsets -> ends
        float* __restrict__ fcsr,          // (B, N, 64)
        int N) {
    const int b = blockIdx.y;
    const int n0 = blockIdx.x * 64;
    const int tid = threadIdx.x;

    __shared__ float t[64][65];
    __shared__ int posb[64];
    if (tid < 64) {
        const int id = idx[(size_t)b * N + n0 + tid];
        posb[tid] = atomicAdd(&off[(size_t)b * R3 + id], 1);
    }

    const float* fb = feats + (size_t)b * 64 * N;
    #pragma unroll
    for (int k = 0; k < 4; ++k) {
        const int d = (tid >> 4) + k * 16;
        const int c = (tid & 15) * 4;
        float4 v = *(const float4*)(fb + (size_t)d * N + n0 + c);
        t[d][c + 0] = v.x; t[d][c + 1] = v.y;
        t[d][c + 2] = v.z; t[d][c + 3] = v.w;
    }
    __syncthreads();

    // 4 threads per point-row; each writes 64B contiguous (4x float4).
    const int j = tid >> 2;            // local point 0..63
    const int d_base = (tid & 3) * 16; // 0,16,32,48
    float* dst = fcsr + ((size_t)b * N + posb[j]) * 64 + d_base;
    #pragma unroll
    for (int q = 0; q < 4; ++q) {
        const int d0 = d_base + q * 4;
        float4 o = make_float4(t[d0][j], t[d0 + 1][j], t[d0 + 2][j], t[d0 + 3][j]);
        *(float4*)(dst + q * 4) = o;
    }
}

// ---------------------------------------------------------------------------
// K3 v6: Round-3's v4 csr_sum (proven to run) + the ONE high-confidence fix.
// Round-3 post-mortem revision: v4's loads were ALREADY coalesced (lane
// spans d=0..63 -> each row load is one contiguous 256B wave transaction).
// The real defect was CU-aliasing: grid (256,B) gave block g of EVERY batch
// the same spatial voxel group, so the CU owning the Gaussian-center plane
// did ~3.5x mean work 16x over (occupancy 34%, tail-bound). Fix: rotate the
// group per batch, g = (bx + 16*b) & 255 (bijective; gridDim.x==256==R3/128
// by launch contract). v5's wide-load restructure is dropped: never ran in
// 2 attempts (container died), and it addressed a mis-diagnosis.
// ---------------------------------------------------------------------------
__global__ __launch_bounds__(512) void csr_sum_kernel(
        const float* __restrict__ fcsr,
        const int* __restrict__ off,      // post-permute: off[v] = segment end
        float* __restrict__ vox, int N) {
    const int b = blockIdx.y;
    const int w = threadIdx.x >> 6;
    const int lane = threadIdx.x & 63;   // == d
    const int g = (blockIdx.x + 16 * b) & 255;   // batch-rotated group
    const int vbase = g * 128 + w * 16;
    const int* offb = off + (size_t)b * R3;
    const float* fb = fcsr + (size_t)b * N * 64;

    __shared__ float st[8 * 64 * 17];    // 34816 B

    int pstart = (vbase > 0) ? offb[vbase - 1] : 0;
    for (int vi = 0; vi < 16; ++vi) {
        const int end = offb[vbase + vi];
        const int start = pstart; pstart = end;
        const int len = end - start;
        const float* p = fb + (size_t)start * 64 + lane;
        float r0 = 0.f, r1 = 0.f, r2 = 0.f, r3 = 0.f;
        int j = 0;
        for (; j + 4 <= len; j += 4) {
            r0 += p[(size_t)(j + 0) * 64];
            r1 += p[(size_t)(j + 1) * 64];
            r2 += p[(size_t)(j + 2) * 64];
            r3 += p[(size_t)(j + 3) * 64];
        }
        for (; j < len; ++j) r0 += p[(size_t)j * 64];
        float r = (r0 + r1) + (r2 + r3);
        r = __fdividef(r, (float)(len > 1 ? len : 1));
        st[(w * 64 + lane) * 17 + vi] = r;
    }
    __syncthreads();

    float* vb = vox + (size_t)b * 64 * R3;
    #pragma unroll
    for (int k = 0; k < 4; ++k) {
        const int d = k * 16 + (lane >> 2);
        const int vi0 = (lane & 3) * 4;
        const float* s = &st[(w * 64 + d) * 17 + vi0];
        float4 o = make_float4(s[0], s[1], s[2], s[3]);
        *(float4*)(vb + (size_t)d * R3 + vbase + vi0) = o;
    }
}

// ---------------------------------------------------------------------------
// K3 fallback (D != 64 or workspace too small): round-1's LDS-atomic
// scatter (measured 186 us). Guarantees no-regression if guards fail.
// ---------------------------------------------------------------------------
__global__ __launch_bounds__(1024, 8) void reduce_kernel(
        const float* __restrict__ feats,
        const int* __restrict__ idx,
        const int* __restrict__ counts,
        float* __restrict__ vox, int D, int N) {
    const int d = blockIdx.x;
    const int b = blockIdx.y;
    const int lo = (int)blockIdx.z * HALF;
    const int tid = threadIdx.x;

    __shared__ float acc[HALF];
    {
        float4* a4 = (float4*)acc;
        const float4 z = make_float4(0.f, 0.f, 0.f, 0.f);
        for (int v = tid; v < (HALF >> 2); v += 1024) a4[v] = z;
    }
    __syncthreads();

    const float* frow = feats + ((size_t)b * D + d) * N;
    const int* irow = idx + (size_t)b * N;
    const int nvec = N >> 2;
    const float4* f4p = (const float4*)frow;
    const int4* i4p = (const int4*)irow;

    #define SCATTER4(f, i)                                                       \
    {                                                                            \
        unsigned a0 = (unsigned)((i).x - lo);                                    \
        if (a0 < (unsigned)HALF) fadd_native(&acc[a0], (f).x);                   \
        unsigned a1 = (unsigned)((i).y - lo);                                    \
        if (a1 < (unsigned)HALF) fadd_native(&acc[a1], (f).y);                   \
        unsigned a2 = (unsigned)((i).z - lo);                                    \
        if (a2 < (unsigned)HALF) fadd_native(&acc[a2], (f).z);                   \
        unsigned a3 = (unsigned)((i).w - lo);                                    \
        if (a3 < (unsigned)HALF) fadd_native(&acc[a3], (f).w);                   \
    }

    if (tid < nvec) {
        float4 f = f4p[tid];
        int4   i = i4p[tid];
        for (int n = tid + 1024; n < nvec; n += 1024) {
            float4 fn = f4p[n];
            int4   in_ = i4p[n];
            SCATTER4(f, i)
            f = fn; i = in_;
        }
        SCATTER4(f, i)
    }
    #undef SCATTER4

    if (tid == 0) {
        for (int n = nvec << 2; n < N; ++n) {
            unsigned a = (unsigned)(irow[n] - lo);
            if (a < (unsigned)HALF) fadd_native(&acc[a], frow[n]);
        }
    }
    __syncthreads();

    const int* crow = counts + (size_t)b * R3 + lo;
    float* vrow = vox + ((size_t)b * D + d) * R3 + lo;
    const int4* c4 = (const int4*)crow;
    float4* v4 = (float4*)vrow;
    for (int v = tid; v < (HALF >> 2); v += 1024) {
        int4 c = c4[v];
        float4 a = ((const float4*)acc)[v];
        a.x = __fdividef(a.x, (float)(c.x > 1 ? c.x : 1));
        a.y = __fdividef(a.y, (float)(c.y > 1 ? c.y : 1));
        a.z = __fdividef(a.z, (float)(c.z > 1 ? c.z : 1));
        a.w = __fdividef(a.w, (float)(c.w > 1 ? c.w : 1));
        v4[v] = a;
    }
}

extern "C" void kernel_launch(void* const* d_in, const int* in_sizes, int n_in,
                              void* d_out, int out_size, void* d_ws, size_t ws_size,
                              hipStream_t stream) {
    const float* feats  = (const float*)d_in[0];   // (B, D, N)
    const float* coords = (const float*)d_in[1];   // (B, 3, N)
    float* out = (float*)d_out;

    const int D = (int)(3LL * in_sizes[0] / in_sizes[1]);
    const int B = (int)((long long)(out_size - in_sizes[1]) / ((long long)D * R3));
    const int N = in_sizes[1] / (3 * B);

    float* vox_out = out;                          // (B, D, R3)
    float* nc_out  = out + (size_t)B * D * R3;     // (B, 3, N)

    // ws layout:
    // [accum B*4 f @0][maxsq B u32 @1024][counts/offsets B*R3 i32 @4096]
    // [idx B*N i32][fcsr B*N*64 f, 256B-aligned]  (fcsr only on CSR path)
    float*    accum  = (float*)d_ws;
    unsigned* maxsq  = (unsigned*)((char*)d_ws + 1024);
    int*      counts = (int*)((char*)d_ws + 4096);
    size_t    idx_off  = 4096 + (size_t)B * R3 * sizeof(int);
    int*      idx    = (int*)((char*)d_ws + idx_off);
    size_t    fcsr_off = (idx_off + (size_t)B * N * sizeof(int) + 255) & ~(size_t)255;
    float*    fcsr  = (float*)((char*)d_ws + fcsr_off);
    const size_t ws_need = fcsr_off + (size_t)B * N * 64 * sizeof(float);

    hipMemsetAsync(d_ws, 0, 4096 + (size_t)B * R3 * sizeof(int), stream);

    sums_kernel <<<dim3(8, B), dim3(256), 0, stream>>>(coords, accum, N);
    maxn_kernel <<<dim3(8, B), dim3(256), 0, stream>>>(coords, accum, maxsq, N);

    const int nvec = (N + 3) >> 2;
    point_kernel<<<dim3((nvec + 255) / 256, B), dim3(256), 0, stream>>>(
        coords, accum, maxsq, nc_out, idx, counts, N);

    if (D == 64 && (N & 63) == 0 && ws_size >= ws_need) {
        // CSR path: counts -> offsets, permute feats into voxel-sorted order,
        // then atomic-free fully-coalesced streaming segment sum.
        prefix_kernel <<<dim3(B), dim3(1024), 0, stream>>>(counts);
        permute_kernel<<<dim3(N / 64, B), dim3(256), 0, stream>>>(
            feats, idx, counts, fcsr, N);
        csr_sum_kernel<<<dim3(R3 / 128, B), dim3(512), 0, stream>>>(
            fcsr, counts, vox_out, N);
    } else {
        reduce_kernel<<<dim3(D, B, 2), dim3(1024), 0, stream>>>(
            feats, idx, counts, vox_out, D, N);
    }
}

// Round 7
// 386.391 us; speedup vs baseline: 1.1101x; 1.1101x over previous
//
#include <hip/hip_runtime.h>

#define RES 32
#define R3 (RES * RES * RES)
#define HALF (R3 / 2)

// Native no-return fp32 atomic add (ds_add_f32 / global_atomic_add_f32).
__device__ __forceinline__ void fadd_native(float* p, float v) {
    unsafeAtomicAdd(p, v);
}

// ---------------------------------------------------------------------------
// K1a: partial coordinate sums, float4 loads. grid (8, B), block 256.
// NUMERICALLY FROZEN: summation order determines mean -> rintf voxel
// boundaries. Do not restructure (absmax margin is thin).
// ---------------------------------------------------------------------------
__global__ void sums_kernel(const float* __restrict__ coords,
                            float* __restrict__ accum, int N) {
    const int b = blockIdx.y;
    const int stride = gridDim.x * blockDim.x;
    const float* cb = coords + (size_t)b * 3 * N;
    const int nvec = N >> 2;
    const float4* c0 = (const float4*)cb;
    const float4* c1 = (const float4*)(cb + N);
    const float4* c2 = (const float4*)(cb + 2 * N);

    float s0 = 0.f, s1 = 0.f, s2 = 0.f;
    for (int n = blockIdx.x * blockDim.x + threadIdx.x; n < nvec; n += stride) {
        float4 a = c0[n]; s0 += (a.x + a.y) + (a.z + a.w);
        float4 c = c1[n]; s1 += (c.x + c.y) + (c.z + c.w);
        float4 d = c2[n]; s2 += (d.x + d.y) + (d.z + d.w);
    }
    if (blockIdx.x == 0 && threadIdx.x == 0) {
        for (int n = nvec << 2; n < N; ++n) {
            s0 += cb[n]; s1 += cb[N + n]; s2 += cb[2 * N + n];
        }
    }
    for (int off = 32; off; off >>= 1) {
        s0 += __shfl_down(s0, off);
        s1 += __shfl_down(s1, off);
        s2 += __shfl_down(s2, off);
    }
    __shared__ float r0[4], r1[4], r2[4];
    const int lane = threadIdx.x & 63, wv = threadIdx.x >> 6;
    if (lane == 0) { r0[wv] = s0; r1[wv] = s1; r2[wv] = s2; }
    __syncthreads();
    if (threadIdx.x == 0) {
        float t0 = 0.f, t1 = 0.f, t2 = 0.f;
        const int nw = blockDim.x >> 6;
        for (int w = 0; w < nw; ++w) { t0 += r0[w]; t1 += r1[w]; t2 += r2[w]; }
        fadd_native(&accum[b * 4 + 0], t0);
        fadd_native(&accum[b * 4 + 1], t1);
        fadd_native(&accum[b * 4 + 2], t2);
    }
}

// ---------------------------------------------------------------------------
// K1b: partial max squared centered norm. NUMERICALLY FROZEN.
// ---------------------------------------------------------------------------
__global__ void maxn_kernel(const float* __restrict__ coords,
                            const float* __restrict__ accum,
                            unsigned* __restrict__ maxsq, int N) {
    const int b = blockIdx.y;
    const int stride = gridDim.x * blockDim.x;
    const float* cb = coords + (size_t)b * 3 * N;
    const float m0 = accum[b * 4 + 0] / (float)N;
    const float m1 = accum[b * 4 + 1] / (float)N;
    const float m2 = accum[b * 4 + 2] / (float)N;
    const int nvec = N >> 2;
    const float4* c0 = (const float4*)cb;
    const float4* c1 = (const float4*)(cb + N);
    const float4* c2 = (const float4*)(cb + 2 * N);

    float mx = 0.f;
    for (int n = blockIdx.x * blockDim.x + threadIdx.x; n < nvec; n += stride) {
        float4 a = c0[n], c = c1[n], d = c2[n];
        a.x -= m0; a.y -= m0; a.z -= m0; a.w -= m0;
        c.x -= m1; c.y -= m1; c.z -= m1; c.w -= m1;
        d.x -= m2; d.y -= m2; d.z -= m2; d.w -= m2;
        mx = fmaxf(mx, a.x * a.x + c.x * c.x + d.x * d.x);
        mx = fmaxf(mx, a.y * a.y + c.y * c.y + d.y * d.y);
        mx = fmaxf(mx, a.z * a.z + c.z * c.z + d.z * d.z);
        mx = fmaxf(mx, a.w * a.w + c.w * c.w + d.w * d.w);
    }
    if (blockIdx.x == 0 && threadIdx.x == 0) {
        for (int n = nvec << 2; n < N; ++n) {
            float a = cb[n] - m0, c = cb[N + n] - m1, d = cb[2 * N + n] - m2;
            mx = fmaxf(mx, a * a + c * c + d * d);
        }
    }
    for (int off = 32; off; off >>= 1) mx = fmaxf(mx, __shfl_down(mx, off));
    __shared__ float r0[4];
    const int lane = threadIdx.x & 63, wv = threadIdx.x >> 6;
    if (lane == 0) r0[wv] = mx;
    __syncthreads();
    if (threadIdx.x == 0) {
        const int nw = blockDim.x >> 6;
        for (int w = 0; w < nw; ++w) mx = fmaxf(mx, r0[w]);
        atomicMax(&maxsq[b], __float_as_uint(mx));
    }
}

// ---------------------------------------------------------------------------
// K2: per-point normalize + voxel index + counts. NUMERICALLY FROZEN.
// ---------------------------------------------------------------------------
__global__ void point_kernel(const float* __restrict__ coords,
                             const float* __restrict__ accum,
                             const unsigned* __restrict__ maxsq,
                             float* __restrict__ nc_out,
                             int* __restrict__ idx_out,
                             int* __restrict__ counts, int N) {
    const int n4 = blockIdx.x * blockDim.x + threadIdx.x;
    const int b = blockIdx.y;
    const int nvec = (N + 3) >> 2;
    if (n4 >= nvec) return;

    const float* cb = coords + (size_t)b * 3 * N;
    const float m0 = accum[b * 4 + 0] / (float)N;
    const float m1 = accum[b * 4 + 1] / (float)N;
    const float m2 = accum[b * 4 + 2] / (float)N;
    const float denom = 2.0f * sqrtf(__uint_as_float(maxsq[b]));
    float* ncb = nc_out + (size_t)b * 3 * N;
    int* irow = idx_out + (size_t)b * N;
    int* crow = counts + (size_t)b * R3;

    const int n0 = n4 << 2;
    if (n0 + 3 < N) {
        float4 a = *(const float4*)(cb + n0);
        float4 c = *(const float4*)(cb + N + n0);
        float4 d = *(const float4*)(cb + 2 * N + n0);
        float4 v0, v1, v2;
        int4 id;
        #define PROC(comp)                                                        \
        {                                                                         \
            float x = (a.comp - m0) / denom + 0.5f;                               \
            float y = (c.comp - m1) / denom + 0.5f;                               \
            float z = (d.comp - m2) / denom + 0.5f;                               \
            v0.comp = fminf(fmaxf(x * (float)RES, 0.f), (float)(RES - 1));        \
            v1.comp = fminf(fmaxf(y * (float)RES, 0.f), (float)(RES - 1));        \
            v2.comp = fminf(fmaxf(z * (float)RES, 0.f), (float)(RES - 1));        \
            id.comp = (int)rintf(v0.comp) * RES * RES                             \
                    + (int)rintf(v1.comp) * RES + (int)rintf(v2.comp);            \
        }
        PROC(x) PROC(y) PROC(z) PROC(w)
        #undef PROC
        *(float4*)(ncb + n0) = v0;
        *(float4*)(ncb + N + n0) = v1;
        *(float4*)(ncb + 2 * N + n0) = v2;
        *(int4*)(irow + n0) = id;
        atomicAdd(&crow[id.x], 1);
        atomicAdd(&crow[id.y], 1);
        atomicAdd(&crow[id.z], 1);
        atomicAdd(&crow[id.w], 1);
    } else {
        for (int n = n0; n < N; ++n) {
            float x = (cb[n] - m0) / denom + 0.5f;
            float y = (cb[N + n] - m1) / denom + 0.5f;
            float z = (cb[2 * N + n] - m2) / denom + 0.5f;
            float v0 = fminf(fmaxf(x * (float)RES, 0.f), (float)(RES - 1));
            float v1 = fminf(fmaxf(y * (float)RES, 0.f), (float)(RES - 1));
            float v2 = fminf(fmaxf(z * (float)RES, 0.f), (float)(RES - 1));
            ncb[n] = v0; ncb[N + n] = v1; ncb[2 * N + n] = v2;
            int id = (int)rintf(v0) * RES * RES + (int)rintf(v1) * RES + (int)rintf(v2);
            irow[n] = id;
            atomicAdd(&crow[id], 1);
        }
    }
}

// ---------------------------------------------------------------------------
// K2.5: in-place exclusive prefix scan of counts -> segment offsets.
// ---------------------------------------------------------------------------
__global__ __launch_bounds__(1024) void prefix_kernel(int* __restrict__ cnt) {
    const int b = blockIdx.x;
    int* row = cnt + (size_t)b * R3;
    const int tid = threadIdx.x;

    int c[32];
    int4* r4 = (int4*)(row + tid * 32);
    int sum = 0;
    #pragma unroll
    for (int k = 0; k < 8; ++k) {
        int4 v = r4[k];
        c[k * 4 + 0] = v.x; c[k * 4 + 1] = v.y;
        c[k * 4 + 2] = v.z; c[k * 4 + 3] = v.w;
        sum += (v.x + v.y) + (v.z + v.w);
    }

    __shared__ int sc[1024];
    sc[tid] = sum;
    __syncthreads();
    for (int off = 1; off < 1024; off <<= 1) {
        int v = (tid >= off) ? sc[tid - off] : 0;
        __syncthreads();
        sc[tid] += v;
        __syncthreads();
    }
    int run = sc[tid] - sum;   // exclusive base for this thread's chunk

    #pragma unroll
    for (int k = 0; k < 8; ++k) {
        int4 o;
        o.x = run; run += c[k * 4 + 0];
        o.y = run; run += c[k * 4 + 1];
        o.z = run; run += c[k * 4 + 2];
        o.w = run; run += c[k * 4 + 3];
        r4[k] = o;
    }
}

// ---------------------------------------------------------------------------
// K2.6: permute features into CSR (voxel-sorted) point-major order.
// Block = 64 points x 64 d. All global accesses >=256B contiguous chunks.
// After this kernel off[v] == segment end (cursor trick).
// ---------------------------------------------------------------------------
__global__ __launch_bounds__(256) void permute_kernel(
        const float* __restrict__ feats,   // (B, 64, N)
        const int* __restrict__ idx,       // (B, N) voxel ids from point_kernel
        int* __restrict__ off,             // (B, R3) exclusive offsets -> ends
        float* __restrict__ fcsr,          // (B, N, 64)
        int N) {
    const int b = blockIdx.y;
    const int n0 = blockIdx.x * 64;
    const int tid = threadIdx.x;

    __shared__ float t[64][65];
    __shared__ int posb[64];
    if (tid < 64) {
        const int id = idx[(size_t)b * N + n0 + tid];
        posb[tid] = atomicAdd(&off[(size_t)b * R3 + id], 1);
    }

    const float* fb = feats + (size_t)b * 64 * N;
    #pragma unroll
    for (int k = 0; k < 4; ++k) {
        const int d = (tid >> 4) + k * 16;
        const int c = (tid & 15) * 4;
        float4 v = *(const float4*)(fb + (size_t)d * N + n0 + c);
        t[d][c + 0] = v.x; t[d][c + 1] = v.y;
        t[d][c + 2] = v.z; t[d][c + 3] = v.w;
    }
    __syncthreads();

    // 4 threads per point-row; each writes 64B contiguous (4x float4).
    const int j = tid >> 2;            // local point 0..63
    const int d_base = (tid & 3) * 16; // 0,16,32,48
    float* dst = fcsr + ((size_t)b * N + posb[j]) * 64 + d_base;
    #pragma unroll
    for (int q = 0; q < 4; ++q) {
        const int d0 = d_base + q * 4;
        float4 o = make_float4(t[d0][j], t[d0 + 1][j], t[d0 + 2][j], t[d0 + 3][j]);
        *(float4*)(dst + q * 4) = o;
    }
}

// ---------------------------------------------------------------------------
// K3 v7: memory-level-parallelism edition.
// Round-6 post-mortem: rotation changed NOTHING (138->138us, occ 34->34%)
// => not load-imbalance. Arithmetic pins the limiter: 2048 256B-loads/CU
// taking 331K cycles = 162 cy/load => latency-bound with only ~10 loads in
// flight per CU (4/wave: the 4-unrolled loop waits vmcnt(0) each round;
// fcsr read latency ~1300cy from L3).
// Fix: lane = (sub=row-in-quad, dq=d-quarter). One wave-load = one
// contiguous 1KB transaction covering 4 CSR rows; 4 loads/round = 16 rows
// (4KB) in flight per wave, 4x v6. Mean segment (len~16) = ONE wait.
// Partial round predicated per quad-row (k+sub+4j < len): no OOB ever
// (all rows < len <= N). Cross-sub combine: 8 shfl_xor. Boundaries: one
// lane-parallel load + shfl instead of 17 serialized scalar loads.
// LDS layout + epilogue byte-identical to proven v6.
// ---------------------------------------------------------------------------
__global__ __launch_bounds__(512) void csr_sum_kernel(
        const float* __restrict__ fcsr,
        const int* __restrict__ off,      // post-permute: off[v] = segment end
        float* __restrict__ vox, int N) {
    const int b = blockIdx.y;
    const int w = threadIdx.x >> 6;
    const int lane = threadIdx.x & 63;
    const int sub = lane >> 4;           // row-in-quad 0..3
    const int dq  = lane & 15;           // d-quarter: dims [4dq, 4dq+4)
    const int g = (blockIdx.x + 16 * b) & 255;   // rotation: neutral, kept
    const int vbase = g * 128 + w * 16;
    const int* offb = off + (size_t)b * R3;
    const float* fb = fcsr + (size_t)b * N * 64;

    __shared__ float st[8 * 64 * 17];    // 34816 B (same as v6)

    // 17 segment boundaries for this wave's 16 voxels, one vector load.
    int e = 0;
    {
        const int t = vbase - 1 + lane;
        if (lane < 17) e = (t >= 0) ? offb[t] : 0;
    }

    #define ACC(A, U) { (A).x += (U).x; (A).y += (U).y; (A).z += (U).z; (A).w += (U).w; }

    for (int vi = 0; vi < 16; ++vi) {
        const int start = __shfl(e, vi);
        const int end   = __shfl(e, vi + 1);
        const int len   = end - start;

        // this lane's slot: row (start + sub + r), dims [4dq, 4dq+4)
        const float* p = fb + ((size_t)start + sub) * 64 + dq * 4;
        float4 a0 = make_float4(0.f, 0.f, 0.f, 0.f);
        float4 a1 = make_float4(0.f, 0.f, 0.f, 0.f);
        float4 a2 = make_float4(0.f, 0.f, 0.f, 0.f);
        float4 a3 = make_float4(0.f, 0.f, 0.f, 0.f);

        int k = 0;
        for (; k + 16 <= len; k += 16) {       // full rounds: 16 rows, 4KB in flight
            const float* q = p + (size_t)k * 64;
            float4 u0 = *(const float4*)(q);
            float4 u1 = *(const float4*)(q + 4 * 64);
            float4 u2 = *(const float4*)(q + 8 * 64);
            float4 u3 = *(const float4*)(q + 12 * 64);
            ACC(a0, u0) ACC(a1, u1) ACC(a2, u2) ACC(a3, u3)
        }
        {   // partial round: predicate uniform per 16-lane sub-group, no OOB
            const float* q = p + (size_t)k * 64;
            if (k + sub < len)      { float4 u = *(const float4*)(q);          ACC(a0, u) }
            if (k + sub + 4 < len)  { float4 u = *(const float4*)(q + 4 * 64); ACC(a1, u) }
            if (k + sub + 8 < len)  { float4 u = *(const float4*)(q + 8 * 64); ACC(a2, u) }
            if (k + sub + 12 < len) { float4 u = *(const float4*)(q + 12 * 64); ACC(a3, u) }
        }

        float4 a;
        a.x = (a0.x + a1.x) + (a2.x + a3.x);
        a.y = (a0.y + a1.y) + (a2.y + a3.y);
        a.z = (a0.z + a1.z) + (a2.z + a3.z);
        a.w = (a0.w + a1.w) + (a2.w + a3.w);
        // combine sub-groups: lanes l, l^16, l^32, l^48
        a.x += __shfl_xor(a.x, 16); a.y += __shfl_xor(a.y, 16);
        a.z += __shfl_xor(a.z, 16); a.w += __shfl_xor(a.w, 16);
        a.x += __shfl_xor(a.x, 32); a.y += __shfl_xor(a.y, 32);
        a.z += __shfl_xor(a.z, 32); a.w += __shfl_xor(a.w, 32);

        if (sub == 0) {      // lanes 0..15 write dims [4dq, 4dq+4)
            const float inv = __fdividef(1.f, (float)(len > 1 ? len : 1));
            float* s = &st[(w * 64 + dq * 4) * 17 + vi];
            s[0 * 17] = a.x * inv;
            s[1 * 17] = a.y * inv;
            s[2 * 17] = a.z * inv;
            s[3 * 17] = a.w * inv;
        }
    }
    #undef ACC
    __syncthreads();

    float* vb = vox + (size_t)b * 64 * R3;
    #pragma unroll
    for (int k = 0; k < 4; ++k) {
        const int d = k * 16 + (lane >> 2);
        const int vi0 = (lane & 3) * 4;
        const float* s = &st[(w * 64 + d) * 17 + vi0];
        float4 o = make_float4(s[0], s[1], s[2], s[3]);
        *(float4*)(vb + (size_t)d * R3 + vbase + vi0) = o;
    }
}

// ---------------------------------------------------------------------------
// K3 fallback (D != 64 or workspace too small): round-1's LDS-atomic
// scatter (measured 186 us). Guarantees no-regression if guards fail.
// ---------------------------------------------------------------------------
__global__ __launch_bounds__(1024, 8) void reduce_kernel(
        const float* __restrict__ feats,
        const int* __restrict__ idx,
        const int* __restrict__ counts,
        float* __restrict__ vox, int D, int N) {
    const int d = blockIdx.x;
    const int b = blockIdx.y;
    const int lo = (int)blockIdx.z * HALF;
    const int tid = threadIdx.x;

    __shared__ float acc[HALF];
    {
        float4* a4 = (float4*)acc;
        const float4 z = make_float4(0.f, 0.f, 0.f, 0.f);
        for (int v = tid; v < (HALF >> 2); v += 1024) a4[v] = z;
    }
    __syncthreads();

    const float* frow = feats + ((size_t)b * D + d) * N;
    const int* irow = idx + (size_t)b * N;
    const int nvec = N >> 2;
    const float4* f4p = (const float4*)frow;
    const int4* i4p = (const int4*)irow;

    #define SCATTER4(f, i)                                                       \
    {                                                                            \
        unsigned a0 = (unsigned)((i).x - lo);                                    \
        if (a0 < (unsigned)HALF) fadd_native(&acc[a0], (f).x);                   \
        unsigned a1 = (unsigned)((i).y - lo);                                    \
        if (a1 < (unsigned)HALF) fadd_native(&acc[a1], (f).y);                   \
        unsigned a2 = (unsigned)((i).z - lo);                                    \
        if (a2 < (unsigned)HALF) fadd_native(&acc[a2], (f).z);                   \
        unsigned a3 = (unsigned)((i).w - lo);                                    \
        if (a3 < (unsigned)HALF) fadd_native(&acc[a3], (f).w);                   \
    }

    if (tid < nvec) {
        float4 f = f4p[tid];
        int4   i = i4p[tid];
        for (int n = tid + 1024; n < nvec; n += 1024) {
            float4 fn = f4p[n];
            int4   in_ = i4p[n];
            SCATTER4(f, i)
            f = fn; i = in_;
        }
        SCATTER4(f, i)
    }
    #undef SCATTER4

    if (tid == 0) {
        for (int n = nvec << 2; n < N; ++n) {
            unsigned a = (unsigned)(irow[n] - lo);
            if (a < (unsigned)HALF) fadd_native(&acc[a], frow[n]);
        }
    }
    __syncthreads();

    const int* crow = counts + (size_t)b * R3 + lo;
    float* vrow = vox + ((size_t)b * D + d) * R3 + lo;
    const int4* c4 = (const int4*)crow;
    float4* v4 = (float4*)vrow;
    for (int v = tid; v < (HALF >> 2); v += 1024) {
        int4 c = c4[v];
        float4 a = ((const float4*)acc)[v];
        a.x = __fdividef(a.x, (float)(c.x > 1 ? c.x : 1));
        a.y = __fdividef(a.y, (float)(c.y > 1 ? c.y : 1));
        a.z = __fdividef(a.z, (float)(c.z > 1 ? c.z : 1));
        a.w = __fdividef(a.w, (float)(c.w > 1 ? c.w : 1));
        v4[v] = a;
    }
}

extern "C" void kernel_launch(void* const* d_in, const int* in_sizes, int n_in,
                              void* d_out, int out_size, void* d_ws, size_t ws_size,
                              hipStream_t stream) {
    const float* feats  = (const float*)d_in[0];   // (B, D, N)
    const float* coords = (const float*)d_in[1];   // (B, 3, N)
    float* out = (float*)d_out;

    const int D = (int)(3LL * in_sizes[0] / in_sizes[1]);
    const int B = (int)((long long)(out_size - in_sizes[1]) / ((long long)D * R3));
    const int N = in_sizes[1] / (3 * B);

    float* vox_out = out;                          // (B, D, R3)
    float* nc_out  = out + (size_t)B * D * R3;     // (B, 3, N)

    // ws layout:
    // [accum B*4 f @0][maxsq B u32 @1024][counts/offsets B*R3 i32 @4096]
    // [idx B*N i32][fcsr B*N*64 f, 256B-aligned]  (fcsr only on CSR path)
    float*    accum  = (float*)d_ws;
    unsigned* maxsq  = (unsigned*)((char*)d_ws + 1024);
    int*      counts = (int*)((char*)d_ws + 4096);
    size_t    idx_off  = 4096 + (size_t)B * R3 * sizeof(int);
    int*      idx    = (int*)((char*)d_ws + idx_off);
    size_t    fcsr_off = (idx_off + (size_t)B * N * sizeof(int) + 255) & ~(size_t)255;
    float*    fcsr  = (float*)((char*)d_ws + fcsr_off);
    const size_t ws_need = fcsr_off + (size_t)B * N * 64 * sizeof(float);

    hipMemsetAsync(d_ws, 0, 4096 + (size_t)B * R3 * sizeof(int), stream);

    sums_kernel <<<dim3(8, B), dim3(256), 0, stream>>>(coords, accum, N);
    maxn_kernel <<<dim3(8, B), dim3(256), 0, stream>>>(coords, accum, maxsq, N);

    const int nvec = (N + 3) >> 2;
    point_kernel<<<dim3((nvec + 255) / 256, B), dim3(256), 0, stream>>>(
        coords, accum, maxsq, nc_out, idx, counts, N);

    if (D == 64 && (N & 63) == 0 && ws_size >= ws_need) {
        // CSR path: counts -> offsets, permute feats into voxel-sorted order,
        // then atomic-free fully-coalesced streaming segment sum.
        prefix_kernel <<<dim3(B), dim3(1024), 0, stream>>>(counts);
        permute_kernel<<<dim3(N / 64, B), dim3(256), 0, stream>>>(
            feats, idx, counts, fcsr, N);
        csr_sum_kernel<<<dim3(R3 / 128, B), dim3(512), 0, stream>>>(
            fcsr, counts, vox_out, N);
    } else {
        reduce_kernel<<<dim3(D, B, 2), dim3(1024), 0, stream>>>(
            feats, idx, counts, vox_out, D, N);
    }
}